// Round 10
// baseline (266.044 us; speedup 1.0000x reference)
//
#include <hip/hip_runtime.h>
#include <hip/hip_bf16.h>

typedef __bf16 bf16x8 __attribute__((ext_vector_type(8)));
typedef float  f32x4  __attribute__((ext_vector_type(4)));
typedef float  f32x8  __attribute__((ext_vector_type(8)));

#define EPSV 1e-5f

// ---------------------------------------------------------------------------
// K1 (grid 288): blocks 0..255: A = x@Wa^T, B = x@Wb^T + stats atomics.
// blocks 256..287: W2 f32 -> bf16 permuted into MFMA B-fragment order:
//   4B chunk c = ((ks*8+nt)*64 + quad*16 + col)*4 + pair
//   elem: k_out = nt*16+col, hch = ks*32+quad*8+pair*2
// ---------------------------------------------------------------------------
__global__ __launch_bounds__(256) void k_ab(const float* __restrict__ x,
                                            const float* __restrict__ W1,
                                            const float* __restrict__ W2,
                                            float* __restrict__ A,
                                            float* __restrict__ Bm,
                                            float* __restrict__ gs,
                                            unsigned int* __restrict__ w2p) {
  __shared__ float xs[4 * 128];
  int t = threadIdx.x;
  if (blockIdx.x >= 256) {  // W2 prep
    int c = (blockIdx.x - 256) * 256 + t;  // 0..8191
    int pair = c & 3;
    int col  = (c >> 2) & 15;
    int quad = (c >> 6) & 3;
    int nt   = (c >> 8) & 7;
    int ks   = (c >> 11) & 3;
    int k = nt * 16 + col;
    int hch = ks * 32 + quad * 8 + pair * 2;
    __bf16 b0 = (__bf16)W2[k * 128 + hch];
    __bf16 b1 = (__bf16)W2[k * 128 + hch + 1];
    unsigned int u0 = *(unsigned short*)&b0, u1 = *(unsigned short*)&b1;
    w2p[c] = u0 | (u1 << 16);
    return;
  }
  int j0 = blockIdx.x * 4;
  for (int idx = t; idx < 512; idx += 256) xs[idx] = x[j0 * 128 + idx];
  __syncthreads();
  int h = t & 127, half = t >> 7;
  const float4* wrow = (const float4*)(W1 + h * 256 + half * 128);
  const float4* xs4 = (const float4*)xs;
  float a0 = 0.f, a1 = 0.f, a2 = 0.f, a3 = 0.f;
#pragma unroll 8
  for (int ch = 0; ch < 32; ++ch) {
    float4 wv = wrow[ch];
    float4 x0 = xs4[ch], x1 = xs4[32 + ch], x2 = xs4[64 + ch], x3 = xs4[96 + ch];
    a0 += wv.x * x0.x + wv.y * x0.y + wv.z * x0.z + wv.w * x0.w;
    a1 += wv.x * x1.x + wv.y * x1.y + wv.z * x1.z + wv.w * x1.w;
    a2 += wv.x * x2.x + wv.y * x2.y + wv.z * x2.z + wv.w * x2.w;
    a3 += wv.x * x3.x + wv.y * x3.y + wv.z * x3.z + wv.w * x3.w;
  }
  float* dst = half ? Bm : A;
  dst[(j0 + 0) * 128 + h] = a0;
  dst[(j0 + 1) * 128 + h] = a1;
  dst[(j0 + 2) * 128 + h] = a2;
  dst[(j0 + 3) * 128 + h] = a3;
  float s = a0 + a1 + a2 + a3;
  float q = a0 * a0 + a1 * a1 + a2 * a2 + a3 * a3;
  atomicAdd(&gs[half * 256 + h], s);
  atomicAdd(&gs[half * 256 + 128 + h], q);
}

// ---------------------------------------------------------------------------
// K2: BN1 fold (recomputed per block) + apply.
// Bt natural row-major. At written PERMUTED (Ap) into A-fragment order for
// 32-ROW slices (k_pass stages linearly, ds_read stride-1 conflict-free):
//   j: S = j>>5 (32 slices), r = (j>>4)&1, col = j&15
//   h4 = c4*4: ks = h4>>5, q = (h4>>3)&3, eh = (h4>>2)&1
//   float4 unit dst = S*1024 + eh*512 + (r*4+ks)*64 + q*16 + col. grid 128.
// ---------------------------------------------------------------------------
__global__ __launch_bounds__(256) void k_fold_apply(const float* __restrict__ gs,
                                                    const float* __restrict__ g1,
                                                    const float* __restrict__ be1,
                                                    const float* __restrict__ A,
                                                    const float* __restrict__ Bm,
                                                    float* __restrict__ Ap,
                                                    float* __restrict__ Bt) {
  __shared__ float sc_s[128], ta_s[128], tb_s[128];
  int t = threadIdx.x;
  if (t < 128) {
    const float inv = 1.f / 1024.f;
    float mA = gs[t] * inv;
    float vA = gs[128 + t] * inv - mA * mA;
    float mB = gs[256 + t] * inv;
    float vB = gs[384 + t] * inv - mB * mB;
    float sc = g1[t] * rsqrtf(vA + vB + EPSV);
    sc_s[t] = sc;
    ta_s[t] = be1[t] - mA * sc;
    tb_s[t] = -mB * sc;
  }
  __syncthreads();
  int idx4 = blockIdx.x * 256 + t;  // 32768 float4 chunks
  int c4 = idx4 & 31;
  float4 sc = ((const float4*)sc_s)[c4];
  float4 ta = ((const float4*)ta_s)[c4];
  float4 tb = ((const float4*)tb_s)[c4];
  float4 a = ((const float4*)A)[idx4];
  float4 b = ((const float4*)Bm)[idx4];
  float4 oa, ob;
  oa.x = fmaf(a.x, sc.x, ta.x); oa.y = fmaf(a.y, sc.y, ta.y);
  oa.z = fmaf(a.z, sc.z, ta.z); oa.w = fmaf(a.w, sc.w, ta.w);
  ob.x = fmaf(b.x, sc.x, tb.x); ob.y = fmaf(b.y, sc.y, tb.y);
  ob.z = fmaf(b.z, sc.z, tb.z); ob.w = fmaf(b.w, sc.w, tb.w);
  // permuted At store (32-row slices)
  int j = idx4 >> 5;
  int h4 = c4 << 2;
  int S = j >> 5, r = (j >> 4) & 1, col = j & 15;
  int ks = h4 >> 5, q = (h4 >> 3) & 3, eh = (h4 >> 2) & 1;
  int dst4 = S * 1024 + eh * 512 + (r * 4 + ks) * 64 + q * 16 + col;
  ((float4*)Ap)[dst4] = oa;
  ((float4*)Bt)[idx4] = ob;
}

// ---------------------------------------------------------------------------
// build fragment: relu(At_slice + Bt_regs) -> bf16x8 (Bt f32 regs: no unpack)
// ---------------------------------------------------------------------------
__device__ __forceinline__ bf16x8 build_r(f32x4 alo, f32x4 ahi,
                                          f32x4 blo, f32x4 bhi) {
  f32x4 z = {0.f, 0.f, 0.f, 0.f};
  f32x4 h0 = __builtin_elementwise_max(alo + blo, z);
  f32x4 h1 = __builtin_elementwise_max(ahi + bhi, z);
  f32x8 h = __builtin_shufflevector(h0, h1, 0, 1, 2, 3, 4, 5, 6, 7);
  return __builtin_convertvector(h, bf16x8);
}

// ---------------------------------------------------------------------------
// Main pass v10: occupancy-first. W2 in LDS (32 KB, fragment order,
// lane-linear conflict-free) instead of 128 VGPRs; Bt wave rows in 64 f32
// regs (s-invariant, no unpack VALU); At 32-row slice in LDS (16 KB,
// fragment order). Target: regs ~165 -> 3 waves/SIMD, LDS 52 KB ->
// 3 blocks/CU (12 waves/CU, was 2 waves/SIMD at VGPR=176+64agpr).
// Block = 4 waves; wave w: i-rows {bi*8+2w,+1}; j: bj*32..+32 (2 s-iters).
// grid 4096 = bi(128) x bj(32). PASS1 -> atomicAdd sum2; PASS2 -> logits.
// NOTE: plain __launch_bounds__(256) — min-waves clamps spill 100s of MB
// (R3/R4/R5). NOTE: NO cooperative launch (R8 crash).
// ---------------------------------------------------------------------------
template <int PASS>
__global__ __launch_bounds__(256) void k_pass(
    const float* __restrict__ Ap, const float* __restrict__ Bt,
    const unsigned int* __restrict__ w2p,
    float* __restrict__ sum2, const float* __restrict__ g2,
    const float* __restrict__ be2, const float* __restrict__ W3v,
    const float* __restrict__ b3p, float* __restrict__ L) {
  __shared__ float ats[4096];      // At slice f32, fragment order (16 KB)
  __shared__ __bf16 w2s[16384];    // W2 bf16, fragment order (32 KB)
  __shared__ float red[1024];      // params / reductions (4 KB)
  int t = threadIdx.x;
  int bid = blockIdx.x;
  int bj = bid & 31, bi = bid >> 5;
  int lane = t & 63, w = t >> 6;
  int col = lane & 15, quad = lane >> 4;

  // ---- stage At slice (4096 floats, linear): 4 chunks/thread ----
  const float* atsrc = Ap + bj * 4096;
#pragma unroll
  for (int it = 0; it < 4; ++it) {
    int base = w * 1024 + it * 256;  // floats
    __builtin_amdgcn_global_load_lds(
        (const __attribute__((address_space(1))) unsigned int*)(atsrc + base + lane * 4),
        (__attribute__((address_space(3))) unsigned int*)(ats + base),
        16, 0, 0);
  }
  // ---- stage W2 (2048 x 16B chunks, linear): 8 chunks/thread ----
#pragma unroll
  for (int it = 0; it < 8; ++it) {
    int base = w * 512 + it * 64;  // uint chunks of 4
    __builtin_amdgcn_global_load_lds(
        (const __attribute__((address_space(1))) unsigned int*)(w2p + (base + lane) * 4),
        (__attribute__((address_space(3))) unsigned int*)((unsigned int*)w2s + base * 4),
        16, 0, 0);
  }

  // ---- Bt wave rows -> 64 f32 regs (s-invariant; addr depends on quad) ----
  f32x4 btl[2][4], bth[2][4];
  {
    const float* br = Bt + (bi * 8 + w * 2) * 128;
#pragma unroll
    for (int r = 0; r < 2; ++r)
#pragma unroll
      for (int ks = 0; ks < 4; ++ks) {
        btl[r][ks] = *(const f32x4*)(br + r * 128 + ks * 32 + quad * 8);
        bth[r][ks] = *(const f32x4*)(br + r * 128 + ks * 32 + quad * 8 + 4);
      }
  }

  // ---- pass-2 fold params into LDS (not regs: keep hot-loop regs low) ----
  if (PASS == 2 && t < 128) {
    const float invM = 1.f / (1024.f * 1024.f);
    float mdot = sum2[t] * invM;
    float var = sum2[128 + t] * invM - mdot * mdot;
    float alv = g2[t] * rsqrtf(var + EPSV);
    red[t] = alv;
    red[128 + t] = be2[t] - mdot * alv;
    red[256 + t] = W3v[t];
  }
  __syncthreads();  // drains global_load_lds + params visible

  float s1[8], s2[8];
  if (PASS == 1) {
#pragma unroll
    for (int nt = 0; nt < 8; ++nt) { s1[nt] = 0.f; s2[nt] = 0.f; }
  }

#pragma unroll
  for (int s = 0; s < 2; ++s) {
    f32x4 acc[2][8];
#pragma unroll
    for (int mt = 0; mt < 2; ++mt)
#pragma unroll
      for (int nt = 0; nt < 8; ++nt) acc[mt][nt] = (f32x4){0.f, 0.f, 0.f, 0.f};

#pragma unroll
    for (int ks = 0; ks < 4; ++ks) {
      const float* ap = ats + ((s * 4 + ks) * 64 + lane) * 4;
      f32x4 alo = *(const f32x4*)ap;
      f32x4 ahi = *(const f32x4*)(ap + 2048);
      bf16x8 a0 = build_r(alo, ahi, btl[0][ks], bth[0][ks]);
      bf16x8 a1 = build_r(alo, ahi, btl[1][ks], bth[1][ks]);
#pragma unroll
      for (int nt = 0; nt < 8; ++nt) {
        bf16x8 bv = *(const bf16x8*)(w2s + ((ks * 8 + nt) * 64 + lane) * 8);
        acc[0][nt] = __builtin_amdgcn_mfma_f32_16x16x32_bf16(a0, bv, acc[0][nt], 0, 0, 0);
        acc[1][nt] = __builtin_amdgcn_mfma_f32_16x16x32_bf16(a1, bv, acc[1][nt], 0, 0, 0);
      }
    }

    if (PASS == 1) {
#pragma unroll
      for (int nt = 0; nt < 8; ++nt)
#pragma unroll
        for (int mt = 0; mt < 2; ++mt)
#pragma unroll
          for (int r = 0; r < 4; ++r) {
            float d = acc[mt][nt][r];
            s1[nt] += d;
            s2[nt] = fmaf(d, d, s2[nt]);
          }
    } else {
      float b3v = b3p[0];
#pragma unroll
      for (int mt = 0; mt < 2; ++mt) {
        float rsum[4] = {0.f, 0.f, 0.f, 0.f};
#pragma unroll
        for (int nt = 0; nt < 8; ++nt) {
          int k = nt * 16 + col;
          float alv = red[k], uuv = red[128 + k], w3v = red[256 + k];
#pragma unroll
          for (int r = 0; r < 4; ++r) {
            float h = fmaxf(fmaf(acc[mt][nt][r], alv, uuv), 0.f);
            rsum[r] = fmaf(h, w3v, rsum[r]);
          }
        }
#pragma unroll
        for (int r = 0; r < 4; ++r) {
          rsum[r] += __shfl_xor(rsum[r], 1);
          rsum[r] += __shfl_xor(rsum[r], 2);
          rsum[r] += __shfl_xor(rsum[r], 4);
          rsum[r] += __shfl_xor(rsum[r], 8);
        }
        if (col == 0) {
          int i = bi * 8 + w * 2 + mt;
#pragma unroll
          for (int r = 0; r < 4; ++r)
            L[i * 1024 + bj * 32 + s * 16 + quad * 4 + r] = rsum[r] + b3v;
        }
      }
    }
  }

  if (PASS == 1) {
#pragma unroll
    for (int nt = 0; nt < 8; ++nt) {
      s1[nt] += __shfl_xor(s1[nt], 16);
      s1[nt] += __shfl_xor(s1[nt], 32);
      s2[nt] += __shfl_xor(s2[nt], 16);
      s2[nt] += __shfl_xor(s2[nt], 32);
    }
    if (lane < 16) {
#pragma unroll
      for (int nt = 0; nt < 8; ++nt) {
        red[w * 256 + nt * 16 + lane] = s1[nt];
        red[w * 256 + 128 + nt * 16 + lane] = s2[nt];
      }
    }
    __syncthreads();
    float tot = red[t] + red[256 + t] + red[512 + t] + red[768 + t];
    atomicAdd(&sum2[t], tot);
  }
}

// ---------------------------------------------------------------------------
// K5: adj[i,j] = (i==j) ? 0 : sigmoid(0.5*(L[i,j]+L[j,i])). grid 4096 x 256.
// ---------------------------------------------------------------------------
__global__ __launch_bounds__(256) void k_adj(const float* __restrict__ L,
                                             float* __restrict__ out) {
  int idx = blockIdx.x * 256 + threadIdx.x;
  int i = idx >> 10, j = idx & 1023;
  float a = L[i * 1024 + j];
  float b = L[j * 1024 + i];
  float s = 1.f / (1.f + __expf(-0.5f * (a + b)));
  out[idx] = (i == j) ? 0.f : s;
}

// ---------------------------------------------------------------------------
extern "C" void kernel_launch(void* const* d_in, const int* in_sizes, int n_in,
                              void* d_out, int out_size, void* d_ws, size_t ws_size,
                              hipStream_t stream) {
  const float* x   = (const float*)d_in[0];
  const float* W1  = (const float*)d_in[1];
  const float* W2  = (const float*)d_in[3];
  const float* W3  = (const float*)d_in[5];
  const float* b3  = (const float*)d_in[6];
  const float* g1  = (const float*)d_in[7];
  const float* be1 = (const float*)d_in[8];
  const float* g2  = (const float*)d_in[9];
  const float* be2 = (const float*)d_in[10];

  float* ws = (float*)d_ws;
  float* A        = ws;                 // 131072
  float* Bm       = ws + 131072;        // 131072
  float* Ap       = ws + 262144;        // 131072 (permuted At, 32-row slices)
  float* Bt       = ws + 393216;        // 131072
  unsigned int* w2p = (unsigned int*)(ws + 524288);  // 8192 uints
  float* gs       = ws + 532480;        // 512
  float* sum2     = ws + 532992;        // 256   (contiguous with gs: one memset)
  float* L        = ws + 533248;        // 1048576
  float* out      = (float*)d_out;

  hipMemsetAsync(gs, 0, 768 * sizeof(float), stream);  // gs + sum2

  k_ab<<<288, 256, 0, stream>>>(x, W1, W2, A, Bm, gs, w2p);
  k_fold_apply<<<128, 256, 0, stream>>>(gs, g1, be1, A, Bm, Ap, Bt);
  k_pass<1><<<4096, 256, 0, stream>>>(Ap, Bt, w2p, sum2, nullptr, nullptr, nullptr, nullptr, nullptr);
  k_pass<2><<<4096, 256, 0, stream>>>(Ap, Bt, w2p, sum2, g2, be2, W3, b3, L);
  k_adj<<<4096, 256, 0, stream>>>(L, out);
}

// Round 11
// 246.385 us; speedup vs baseline: 1.0798x; 1.0798x over previous
//
#include <hip/hip_runtime.h>
#include <hip/hip_bf16.h>

typedef __bf16 bf16x8 __attribute__((ext_vector_type(8)));
typedef float  f32x4  __attribute__((ext_vector_type(4)));
typedef float  f32x8  __attribute__((ext_vector_type(8)));

#define EPSV 1e-5f

// ---------------------------------------------------------------------------
// K1 (grid 288): blocks 0..255: A = x@Wa^T (written RAW in permuted MFMA
// A-fragment layout), B = x@Wb^T (natural) + stats atomics.
// Permuted A float index for (j,h):
//   S=j>>6, r16=(j>>4)&3, colj=j&15, ks=h>>5, q=(h>>3)&3, eh=(h>>2)&1, pos=h&3
//   idx = S*8192 + eh*4096 + (r16*4+ks)*256 + q*64 + colj*4 + pos
// blocks 256..287: W2 f32 -> bf16 permuted into MFMA B-fragment order.
// ---------------------------------------------------------------------------
__global__ __launch_bounds__(256) void k_ab(const float* __restrict__ x,
                                            const float* __restrict__ W1,
                                            const float* __restrict__ W2,
                                            float* __restrict__ Ap,
                                            float* __restrict__ Bm,
                                            float* __restrict__ gs,
                                            unsigned int* __restrict__ w2p) {
  __shared__ float xs[4 * 128];
  int t = threadIdx.x;
  if (blockIdx.x >= 256) {  // W2 prep
    int c = (blockIdx.x - 256) * 256 + t;  // 0..8191
    int pair = c & 3;
    int col  = (c >> 2) & 15;
    int quad = (c >> 6) & 3;
    int nt   = (c >> 8) & 7;
    int ks   = (c >> 11) & 3;
    int k = nt * 16 + col;
    int hch = ks * 32 + quad * 8 + pair * 2;
    __bf16 b0 = (__bf16)W2[k * 128 + hch];
    __bf16 b1 = (__bf16)W2[k * 128 + hch + 1];
    unsigned int u0 = *(unsigned short*)&b0, u1 = *(unsigned short*)&b1;
    w2p[c] = u0 | (u1 << 16);
    return;
  }
  int j0 = blockIdx.x * 4;
  for (int idx = t; idx < 512; idx += 256) xs[idx] = x[j0 * 128 + idx];
  __syncthreads();
  int h = t & 127, half = t >> 7;
  const float4* wrow = (const float4*)(W1 + h * 256 + half * 128);
  const float4* xs4 = (const float4*)xs;
  float a0 = 0.f, a1 = 0.f, a2 = 0.f, a3 = 0.f;
#pragma unroll 8
  for (int ch = 0; ch < 32; ++ch) {
    float4 wv = wrow[ch];
    float4 x0 = xs4[ch], x1 = xs4[32 + ch], x2 = xs4[64 + ch], x3 = xs4[96 + ch];
    a0 += wv.x * x0.x + wv.y * x0.y + wv.z * x0.z + wv.w * x0.w;
    a1 += wv.x * x1.x + wv.y * x1.y + wv.z * x1.z + wv.w * x1.w;
    a2 += wv.x * x2.x + wv.y * x2.y + wv.z * x2.z + wv.w * x2.w;
    a3 += wv.x * x3.x + wv.y * x3.y + wv.z * x3.z + wv.w * x3.w;
  }
  if (half == 0) {
    // permuted scatter store of raw A (base for j0, +4 per consecutive j)
    int S = j0 >> 6, r16 = (j0 >> 4) & 3, colj = j0 & 15;
    int ks = h >> 5, q = (h >> 3) & 3, eh = (h >> 2) & 1, pos = h & 3;
    int base = S * 8192 + eh * 4096 + (r16 * 4 + ks) * 256 + q * 64 + colj * 4 + pos;
    Ap[base] = a0;
    Ap[base + 4] = a1;      // colj+1
    Ap[base + 8] = a2;      // colj+2
    Ap[base + 12] = a3;     // colj+3
  } else {
    Bm[(j0 + 0) * 128 + h] = a0;
    Bm[(j0 + 1) * 128 + h] = a1;
    Bm[(j0 + 2) * 128 + h] = a2;
    Bm[(j0 + 3) * 128 + h] = a3;
  }
  float s = a0 + a1 + a2 + a3;
  float q2 = a0 * a0 + a1 * a1 + a2 * a2 + a3 * a3;
  atomicAdd(&gs[half * 256 + h], s);
  atomicAdd(&gs[half * 256 + 128 + h], q2);
}

// ---------------------------------------------------------------------------
// build fragment with inline BN1 fold:
//   h1 = relu( sc*(Araw + Braw) + t ) -> bf16x8
// ---------------------------------------------------------------------------
__device__ __forceinline__ bf16x8 build_fold(f32x4 alo, f32x4 ahi,
                                             const float* __restrict__ bp,
                                             f32x4 sl, f32x4 sh,
                                             f32x4 tl, f32x4 th) {
  f32x4 b0 = *(const f32x4*)bp;
  f32x4 b1 = *(const f32x4*)(bp + 4);
  f32x4 z = {0.f, 0.f, 0.f, 0.f};
  f32x4 h0 = __builtin_elementwise_max((alo + b0) * sl + tl, z);
  f32x4 h1 = __builtin_elementwise_max((ahi + b1) * sh + th, z);
  f32x8 h = __builtin_shufflevector(h0, h1, 0, 1, 2, 3, 4, 5, 6, 7);
  return __builtin_convertvector(h, bf16x8);
}

// ---------------------------------------------------------------------------
// Main pass (R6 structure + inline fold; k_fold_apply dispatch eliminated).
// W2 in 128 VGPRs; raw-A bj-slice (64 rows, permuted fragment order) in LDS
// via linear global_load_lds; raw-B bi-rows in LDS; BN1 fold params sc/t
// computed in prologue (t<128) into LDS, read per-ks as broadcast
// ds_read_b128 (conflict-free).
// Block = 4 waves; wave w: i-rows {bi*8+2w,+1}; j: bj*64..+64 (4 subtiles).
// grid 2048 = bi(128) x bj(16). PASS1 -> atomicAdd sum2; PASS2 -> logits.
// NOTE: plain __launch_bounds__(256) — min-waves clamps spill 100s of MB
// (R3/R4/R5). NO cooperative launch (R8 crash). W2 stays in regs; j-tile
// stays 64 (R10: W2-in-LDS + small tiles = 118 us regression).
// ---------------------------------------------------------------------------
template <int PASS>
__global__ __launch_bounds__(256) void k_pass(
    const float* __restrict__ Ap, const float* __restrict__ Bm,
    const unsigned int* __restrict__ w2p,
    const float* __restrict__ gs, const float* __restrict__ g1,
    const float* __restrict__ be1,
    float* __restrict__ sum2, const float* __restrict__ g2,
    const float* __restrict__ be2, const float* __restrict__ W3v,
    const float* __restrict__ b3p, float* __restrict__ L) {
  __shared__ float lds[8192 + 1024 + 256];  // A slice | B rows | sc/t params
  float* btl = lds + 8192;
  float* prm = lds + 9216;
  int t = threadIdx.x;
  int bid = blockIdx.x;
  int bj = bid & 15, bi = bid >> 4;
  int lane = t & 63, w = t >> 6;
  int col = lane & 15, quad = lane >> 4;

  // ---- stage raw-A slice (8192 floats, linear; already permuted) ----
  const float* atsrc = Ap + bj * 8192;
#pragma unroll
  for (int it = 0; it < 8; ++it) {
    int g = w * 8 + it;
    __builtin_amdgcn_global_load_lds(
        (const __attribute__((address_space(1))) unsigned int*)(atsrc + g * 256 + lane * 4),
        (__attribute__((address_space(3))) unsigned int*)(lds + g * 256),
        16, 0, 0);
  }
  // ---- stage raw-B rows (wave w: its 2 rows = 256 floats) ----
  __builtin_amdgcn_global_load_lds(
      (const __attribute__((address_space(1))) unsigned int*)(Bm + (bi * 8 + w * 2) * 128 + lane * 4),
      (__attribute__((address_space(3))) unsigned int*)(btl + w * 256),
      16, 0, 0);

  // ---- BN1 fold params into LDS: sc = g1*rsqrt(vA+vB+eps), t = be1-(mA+mB)sc
  if (t < 128) {
    const float inv = 1.f / 1024.f;
    float mA = gs[t] * inv;
    float vA = gs[128 + t] * inv - mA * mA;
    float mB = gs[256 + t] * inv;
    float vB = gs[384 + t] * inv - mB * mB;
    float sc = g1[t] * rsqrtf(vA + vB + EPSV);
    prm[t] = sc;
    prm[128 + t] = be1[t] - (mA + mB) * sc;
  }

  // ---- preload W2 fragments into 128 VGPRs (coalesced dwordx4) ----
  bf16x8 bw[4][8];
#pragma unroll
  for (int ks = 0; ks < 4; ++ks)
#pragma unroll
    for (int nt = 0; nt < 8; ++nt)
      bw[ks][nt] = *(const bf16x8*)((const __bf16*)w2p + (((ks * 8 + nt) * 64) + lane) * 8);

  float s1[8], s2[8];
  float al[8], uu[8], w3l[8];
  float b3v = 0.f;
  if (PASS == 1) {
#pragma unroll
    for (int nt = 0; nt < 8; ++nt) { s1[nt] = 0.f; s2[nt] = 0.f; }
  } else {
    b3v = b3p[0];
    const float invM = 1.f / (1024.f * 1024.f);
#pragma unroll
    for (int nt = 0; nt < 8; ++nt) {
      int k = nt * 16 + col;
      float mdot = sum2[k] * invM;
      float var = sum2[128 + k] * invM - mdot * mdot;
      float alv = g2[k] * rsqrtf(var + EPSV);
      al[nt] = alv;
      uu[nt] = be2[k] - mdot * alv;
      w3l[nt] = W3v[k];
    }
  }
  __syncthreads();  // drains global_load_lds + prm visible

  const float* bp0 = btl + w * 256;
  const float* bp1 = bp0 + 128;

  for (int s = 0; s < 4; ++s) {
    f32x4 acc[2][8];
#pragma unroll
    for (int mt = 0; mt < 2; ++mt)
#pragma unroll
      for (int nt = 0; nt < 8; ++nt) acc[mt][nt] = (f32x4){0.f, 0.f, 0.f, 0.f};

#pragma unroll
    for (int ks = 0; ks < 4; ++ks) {
      const float* ap = lds + ((s * 4 + ks) * 64 + lane) * 4;
      f32x4 alo = *(const f32x4*)ap;
      f32x4 ahi = *(const f32x4*)(ap + 4096);
      int po = ks * 32 + quad * 8;
      f32x4 sl = *(const f32x4*)(prm + po);
      f32x4 sh = *(const f32x4*)(prm + po + 4);
      f32x4 tl = *(const f32x4*)(prm + 128 + po);
      f32x4 th = *(const f32x4*)(prm + 128 + po + 4);
      bf16x8 a0 = build_fold(alo, ahi, bp0 + po, sl, sh, tl, th);
      bf16x8 a1 = build_fold(alo, ahi, bp1 + po, sl, sh, tl, th);
#pragma unroll
      for (int nt = 0; nt < 8; ++nt) {
        acc[0][nt] = __builtin_amdgcn_mfma_f32_16x16x32_bf16(a0, bw[ks][nt], acc[0][nt], 0, 0, 0);
        acc[1][nt] = __builtin_amdgcn_mfma_f32_16x16x32_bf16(a1, bw[ks][nt], acc[1][nt], 0, 0, 0);
      }
    }

    if (PASS == 1) {
#pragma unroll
      for (int nt = 0; nt < 8; ++nt)
#pragma unroll
        for (int mt = 0; mt < 2; ++mt)
#pragma unroll
          for (int r = 0; r < 4; ++r) {
            float d = acc[mt][nt][r];
            s1[nt] += d;
            s2[nt] = fmaf(d, d, s2[nt]);
          }
    } else {
#pragma unroll
      for (int mt = 0; mt < 2; ++mt) {
        float rsum[4] = {0.f, 0.f, 0.f, 0.f};
#pragma unroll
        for (int nt = 0; nt < 8; ++nt)
#pragma unroll
          for (int r = 0; r < 4; ++r) {
            float h = fmaxf(fmaf(acc[mt][nt][r], al[nt], uu[nt]), 0.f);
            rsum[r] = fmaf(h, w3l[nt], rsum[r]);
          }
#pragma unroll
        for (int r = 0; r < 4; ++r) {
          rsum[r] += __shfl_xor(rsum[r], 1);
          rsum[r] += __shfl_xor(rsum[r], 2);
          rsum[r] += __shfl_xor(rsum[r], 4);
          rsum[r] += __shfl_xor(rsum[r], 8);
        }
        if (col == 0) {
          int i = bi * 8 + w * 2 + mt;
          float4 v = make_float4(rsum[0] + b3v, rsum[1] + b3v,
                                 rsum[2] + b3v, rsum[3] + b3v);
          *(float4*)(&L[i * 1024 + bj * 64 + s * 16 + quad * 4]) = v;
        }
      }
    }
  }

  if (PASS == 1) {
#pragma unroll
    for (int nt = 0; nt < 8; ++nt) {
      s1[nt] += __shfl_xor(s1[nt], 16);
      s1[nt] += __shfl_xor(s1[nt], 32);
      s2[nt] += __shfl_xor(s2[nt], 16);
      s2[nt] += __shfl_xor(s2[nt], 32);
    }
    __syncthreads();  // all A reads done before reduction aliases lds
    if (lane < 16) {
#pragma unroll
      for (int nt = 0; nt < 8; ++nt) {
        lds[w * 256 + nt * 16 + lane] = s1[nt];
        lds[w * 256 + 128 + nt * 16 + lane] = s2[nt];
      }
    }
    __syncthreads();
    float tot = lds[t] + lds[256 + t] + lds[512 + t] + lds[768 + t];
    atomicAdd(&sum2[t], tot);
  }
}

// ---------------------------------------------------------------------------
// K5: adj[i,j] = (i==j) ? 0 : sigmoid(0.5*(L[i,j]+L[j,i])). grid 4096 x 256.
// ---------------------------------------------------------------------------
__global__ __launch_bounds__(256) void k_adj(const float* __restrict__ L,
                                             float* __restrict__ out) {
  int idx = blockIdx.x * 256 + threadIdx.x;
  int i = idx >> 10, j = idx & 1023;
  float a = L[i * 1024 + j];
  float b = L[j * 1024 + i];
  float s = 1.f / (1.f + __expf(-0.5f * (a + b)));
  out[idx] = (i == j) ? 0.f : s;
}

// ---------------------------------------------------------------------------
extern "C" void kernel_launch(void* const* d_in, const int* in_sizes, int n_in,
                              void* d_out, int out_size, void* d_ws, size_t ws_size,
                              hipStream_t stream) {
  const float* x   = (const float*)d_in[0];
  const float* W1  = (const float*)d_in[1];
  const float* W2  = (const float*)d_in[3];
  const float* W3  = (const float*)d_in[5];
  const float* b3  = (const float*)d_in[6];
  const float* g1  = (const float*)d_in[7];
  const float* be1 = (const float*)d_in[8];
  const float* g2  = (const float*)d_in[9];
  const float* be2 = (const float*)d_in[10];

  float* ws = (float*)d_ws;
  float* Ap       = ws;                 // 131072 (raw A, permuted layout)
  float* Bm       = ws + 131072;        // 131072 (raw B, natural)
  unsigned int* w2p = (unsigned int*)(ws + 262144);  // 8192 uints
  float* gs       = ws + 270336;        // 512
  float* sum2     = ws + 270848;        // 256   (contiguous with gs: one memset)
  float* L        = ws + 271104;        // 1048576
  float* out      = (float*)d_out;

  hipMemsetAsync(gs, 0, 768 * sizeof(float), stream);  // gs + sum2

  k_ab<<<288, 256, 0, stream>>>(x, W1, W2, Ap, Bm, gs, w2p);
  k_pass<1><<<2048, 256, 0, stream>>>(Ap, Bm, w2p, gs, g1, be1, sum2,
                                      nullptr, nullptr, nullptr, nullptr, nullptr);
  k_pass<2><<<2048, 256, 0, stream>>>(Ap, Bm, w2p, gs, g1, be1, sum2,
                                      g2, be2, W3, b3, L);
  k_adj<<<4096, 256, 0, stream>>>(L, out);
}

// Round 12
// 217.383 us; speedup vs baseline: 1.2239x; 1.1334x over previous
//
#include <hip/hip_runtime.h>
#include <hip/hip_bf16.h>

typedef _Float16 f16x8 __attribute__((ext_vector_type(8)));
typedef _Float16 f16x4 __attribute__((ext_vector_type(4)));
typedef float    f32x4 __attribute__((ext_vector_type(4)));

#define EPSV 1e-5f

// ---------------------------------------------------------------------------
// K1 (grid 288): blocks 0..255: A = x@Wa^T, B = x@Wb^T (f32 natural) + stats
// atomics. blocks 256..287: W2 f32 -> fp16 permuted into MFMA B-fragment
// order: 4B chunk c = ((ks*8+nt)*64 + quad*16 + col)*4 + pair
//   elem: k_out = nt*16+col, hch = ks*32+quad*8+pair*2
// ---------------------------------------------------------------------------
__global__ __launch_bounds__(256) void k_ab(const float* __restrict__ x,
                                            const float* __restrict__ W1,
                                            const float* __restrict__ W2,
                                            float* __restrict__ A,
                                            float* __restrict__ Bm,
                                            float* __restrict__ gs,
                                            unsigned int* __restrict__ w2p) {
  __shared__ float xs[4 * 128];
  int t = threadIdx.x;
  if (blockIdx.x >= 256) {  // W2 prep -> fp16
    int c = (blockIdx.x - 256) * 256 + t;  // 0..8191
    int pair = c & 3;
    int col  = (c >> 2) & 15;
    int quad = (c >> 6) & 3;
    int nt   = (c >> 8) & 7;
    int ks   = (c >> 11) & 3;
    int k = nt * 16 + col;
    int hch = ks * 32 + quad * 8 + pair * 2;
    _Float16 b0 = (_Float16)W2[k * 128 + hch];
    _Float16 b1 = (_Float16)W2[k * 128 + hch + 1];
    unsigned int u0 = *(unsigned short*)&b0, u1 = *(unsigned short*)&b1;
    w2p[c] = u0 | (u1 << 16);
    return;
  }
  int j0 = blockIdx.x * 4;
  for (int idx = t; idx < 512; idx += 256) xs[idx] = x[j0 * 128 + idx];
  __syncthreads();
  int h = t & 127, half = t >> 7;
  const float4* wrow = (const float4*)(W1 + h * 256 + half * 128);
  const float4* xs4 = (const float4*)xs;
  float a0 = 0.f, a1 = 0.f, a2 = 0.f, a3 = 0.f;
#pragma unroll 8
  for (int ch = 0; ch < 32; ++ch) {
    float4 wv = wrow[ch];
    float4 x0 = xs4[ch], x1 = xs4[32 + ch], x2 = xs4[64 + ch], x3 = xs4[96 + ch];
    a0 += wv.x * x0.x + wv.y * x0.y + wv.z * x0.z + wv.w * x0.w;
    a1 += wv.x * x1.x + wv.y * x1.y + wv.z * x1.z + wv.w * x1.w;
    a2 += wv.x * x2.x + wv.y * x2.y + wv.z * x2.z + wv.w * x2.w;
    a3 += wv.x * x3.x + wv.y * x3.y + wv.z * x3.z + wv.w * x3.w;
  }
  float* dst = half ? Bm : A;
  dst[(j0 + 0) * 128 + h] = a0;
  dst[(j0 + 1) * 128 + h] = a1;
  dst[(j0 + 2) * 128 + h] = a2;
  dst[(j0 + 3) * 128 + h] = a3;
  float s = a0 + a1 + a2 + a3;
  float q = a0 * a0 + a1 * a1 + a2 * a2 + a3 * a3;
  atomicAdd(&gs[half * 256 + h], s);
  atomicAdd(&gs[half * 256 + 128 + h], q);
}

// ---------------------------------------------------------------------------
// K2: BN1 fold + apply, output FP16.
// At -> PERMUTED fp16 (Apf) in A-fragment order (16B unit = lane's 8 elems):
//   j: S=j>>6, s=(j>>4)&3, col=j&15 ; h4: ks=h4>>5, quad=(h4>>3)&3, e0=h4&7
//   uint addr = S*4096 + ((s*4+ks)*64 + quad*16 + col)*4 + (e0>>1)  [uint2]
// Bt -> natural row-major fp16 (Btf). grid 128 x 256.
// ---------------------------------------------------------------------------
__global__ __launch_bounds__(256) void k_fold_apply(const float* __restrict__ gs,
                                                    const float* __restrict__ g1,
                                                    const float* __restrict__ be1,
                                                    const float* __restrict__ A,
                                                    const float* __restrict__ Bm,
                                                    unsigned int* __restrict__ Apf,
                                                    unsigned int* __restrict__ Btf) {
  __shared__ float sc_s[128], ta_s[128], tb_s[128];
  int t = threadIdx.x;
  if (t < 128) {
    const float inv = 1.f / 1024.f;
    float mA = gs[t] * inv;
    float vA = gs[128 + t] * inv - mA * mA;
    float mB = gs[256 + t] * inv;
    float vB = gs[384 + t] * inv - mB * mB;
    float sc = g1[t] * rsqrtf(vA + vB + EPSV);
    sc_s[t] = sc;
    ta_s[t] = be1[t] - mA * sc;
    tb_s[t] = -mB * sc;
  }
  __syncthreads();
  int idx4 = blockIdx.x * 256 + t;  // 32768 float4 chunks
  int c4 = idx4 & 31;
  f32x4 sc = ((const f32x4*)sc_s)[c4];
  f32x4 ta = ((const f32x4*)ta_s)[c4];
  f32x4 tb = ((const f32x4*)tb_s)[c4];
  f32x4 a = ((const f32x4*)A)[idx4];
  f32x4 b = ((const f32x4*)Bm)[idx4];
  f32x4 oa = a * sc + ta;
  f32x4 ob = b * sc + tb;
  f16x4 oah = __builtin_convertvector(oa, f16x4);
  f16x4 obh = __builtin_convertvector(ob, f16x4);
  // permuted At store (uint2 = 4 fp16)
  int j = idx4 >> 5;
  int h4 = c4 << 2;
  int S = j >> 6, s = (j >> 4) & 3, col = j & 15;
  int ks = h4 >> 5, quad = (h4 >> 3) & 3, e0 = h4 & 7;
  int au = S * 4096 + ((s * 4 + ks) * 64 + quad * 16 + col) * 4 + (e0 >> 1);
  *(uint2*)(Apf + au) = *(uint2*)&oah;
  *(uint2*)(Btf + idx4 * 2) = *(uint2*)&obh;
}

// ---------------------------------------------------------------------------
// Main pass v12: FP16 datapath. W2 fp16 in 128 VGPRs; Bt wave rows pre-folded
// fp16 in 32 VGPRs (s-invariant, added directly via v_pk_add_f16 — no unpack,
// no convert); At fp16 fragment-permuted in LDS (16 KB): ONE ds_read_b128 per
// ks (was 6 in the f32/bf16 path). mfma_f32_16x16x32_f16 (same layout/rate as
// bf16). Block = 4 waves; wave w: i-rows {bi*8+2w,+1}; j: bj*64..+64.
// grid 2048 = bi(128) x bj(16). PASS1 -> atomicAdd sum2; PASS2 -> logits.
// NOTE: plain __launch_bounds__(256) — min-waves clamps spill 100s of MB
// (R3/R4/R5). NO cooperative launch (R8). W2 stays in regs, j-tile 64 (R10).
// ---------------------------------------------------------------------------
template <int PASS>
__global__ __launch_bounds__(256) void k_pass(
    const unsigned int* __restrict__ Apf, const unsigned int* __restrict__ Btf,
    const unsigned int* __restrict__ w2p,
    float* __restrict__ sum2, const float* __restrict__ g2,
    const float* __restrict__ be2, const float* __restrict__ W3v,
    const float* __restrict__ b3p, float* __restrict__ L) {
  __shared__ unsigned int ats[4096];  // At fp16 slice, fragment order (16 KB)
  __shared__ float red[1024];         // reductions (4 KB)
  int t = threadIdx.x;
  int bid = blockIdx.x;
  int bj = bid & 15, bi = bid >> 4;
  int lane = t & 63, w = t >> 6;
  int col = lane & 15, quad = lane >> 4;

  // ---- stage At slice (4096 uints, linear): 16 insts, 4/wave ----
  const unsigned int* atsrc = Apf + bj * 4096;
#pragma unroll
  for (int it = 0; it < 4; ++it) {
    int g = w * 4 + it;
    __builtin_amdgcn_global_load_lds(
        (const __attribute__((address_space(1))) unsigned int*)(atsrc + g * 256 + lane * 4),
        (__attribute__((address_space(3))) unsigned int*)(ats + g * 256),
        16, 0, 0);
  }

  // ---- Bt wave rows (pre-folded fp16) -> 32 VGPRs (s-invariant) ----
  f16x8 btr[2][4];
  {
    int i0 = bi * 8 + w * 2;
#pragma unroll
    for (int r = 0; r < 2; ++r)
#pragma unroll
      for (int ks = 0; ks < 4; ++ks)
        btr[r][ks] = *(const f16x8*)((const _Float16*)Btf + (i0 + r) * 128 + ks * 32 + quad * 8);
  }

  // ---- preload W2 fp16 fragments into 128 VGPRs (coalesced dwordx4) ----
  f16x8 bw[4][8];
#pragma unroll
  for (int ks = 0; ks < 4; ++ks)
#pragma unroll
    for (int nt = 0; nt < 8; ++nt)
      bw[ks][nt] = *(const f16x8*)((const _Float16*)w2p + (((ks * 8 + nt) * 64) + lane) * 8);

  float s1[8], s2[8];
  float al[8], uu[8], w3l[8];
  float b3v = 0.f;
  if (PASS == 1) {
#pragma unroll
    for (int nt = 0; nt < 8; ++nt) { s1[nt] = 0.f; s2[nt] = 0.f; }
  } else {
    b3v = b3p[0];
    const float invM = 1.f / (1024.f * 1024.f);
#pragma unroll
    for (int nt = 0; nt < 8; ++nt) {
      int k = nt * 16 + col;
      float mdot = sum2[k] * invM;
      float var = sum2[128 + k] * invM - mdot * mdot;
      float alv = g2[k] * rsqrtf(var + EPSV);
      al[nt] = alv;
      uu[nt] = be2[k] - mdot * alv;
      w3l[nt] = W3v[k];
    }
  }
  __syncthreads();  // drains global_load_lds

  const f16x8 zz = {(_Float16)0, (_Float16)0, (_Float16)0, (_Float16)0,
                    (_Float16)0, (_Float16)0, (_Float16)0, (_Float16)0};

  for (int s = 0; s < 4; ++s) {
    f32x4 acc[2][8];
#pragma unroll
    for (int mt = 0; mt < 2; ++mt)
#pragma unroll
      for (int nt = 0; nt < 8; ++nt) acc[mt][nt] = (f32x4){0.f, 0.f, 0.f, 0.f};

#pragma unroll
    for (int ks = 0; ks < 4; ++ks) {
      f16x8 af = *(const f16x8*)(ats + ((s * 4 + ks) * 64 + lane) * 4);
      f16x8 a0 = __builtin_elementwise_max(af + btr[0][ks], zz);
      f16x8 a1 = __builtin_elementwise_max(af + btr[1][ks], zz);
#pragma unroll
      for (int nt = 0; nt < 8; ++nt) {
        acc[0][nt] = __builtin_amdgcn_mfma_f32_16x16x32_f16(a0, bw[ks][nt], acc[0][nt], 0, 0, 0);
        acc[1][nt] = __builtin_amdgcn_mfma_f32_16x16x32_f16(a1, bw[ks][nt], acc[1][nt], 0, 0, 0);
      }
    }

    if (PASS == 1) {
#pragma unroll
      for (int nt = 0; nt < 8; ++nt)
#pragma unroll
        for (int mt = 0; mt < 2; ++mt)
#pragma unroll
          for (int r = 0; r < 4; ++r) {
            float d = acc[mt][nt][r];
            s1[nt] += d;
            s2[nt] = fmaf(d, d, s2[nt]);
          }
    } else {
#pragma unroll
      for (int mt = 0; mt < 2; ++mt) {
        float rsum[4] = {0.f, 0.f, 0.f, 0.f};
#pragma unroll
        for (int nt = 0; nt < 8; ++nt)
#pragma unroll
          for (int r = 0; r < 4; ++r) {
            float h = fmaxf(fmaf(acc[mt][nt][r], al[nt], uu[nt]), 0.f);
            rsum[r] = fmaf(h, w3l[nt], rsum[r]);
          }
#pragma unroll
        for (int r = 0; r < 4; ++r) {
          rsum[r] += __shfl_xor(rsum[r], 1);
          rsum[r] += __shfl_xor(rsum[r], 2);
          rsum[r] += __shfl_xor(rsum[r], 4);
          rsum[r] += __shfl_xor(rsum[r], 8);
        }
        if (col == 0) {
          int i = bi * 8 + w * 2 + mt;
          float4 v = make_float4(rsum[0] + b3v, rsum[1] + b3v,
                                 rsum[2] + b3v, rsum[3] + b3v);
          *(float4*)(&L[i * 1024 + bj * 64 + s * 16 + quad * 4]) = v;
        }
      }
    }
  }

  if (PASS == 1) {
#pragma unroll
    for (int nt = 0; nt < 8; ++nt) {
      s1[nt] += __shfl_xor(s1[nt], 16);
      s1[nt] += __shfl_xor(s1[nt], 32);
      s2[nt] += __shfl_xor(s2[nt], 16);
      s2[nt] += __shfl_xor(s2[nt], 32);
    }
    if (lane < 16) {
#pragma unroll
      for (int nt = 0; nt < 8; ++nt) {
        red[w * 256 + nt * 16 + lane] = s1[nt];
        red[w * 256 + 128 + nt * 16 + lane] = s2[nt];
      }
    }
    __syncthreads();
    float tot = red[t] + red[256 + t] + red[512 + t] + red[768 + t];
    atomicAdd(&sum2[t], tot);
  }
}

// ---------------------------------------------------------------------------
// K5: adj[i,j] = (i==j) ? 0 : sigmoid(0.5*(L[i,j]+L[j,i])). grid 4096 x 256.
// ---------------------------------------------------------------------------
__global__ __launch_bounds__(256) void k_adj(const float* __restrict__ L,
                                             float* __restrict__ out) {
  int idx = blockIdx.x * 256 + threadIdx.x;
  int i = idx >> 10, j = idx & 1023;
  float a = L[i * 1024 + j];
  float b = L[j * 1024 + i];
  float s = 1.f / (1.f + __expf(-0.5f * (a + b)));
  out[idx] = (i == j) ? 0.f : s;
}

// ---------------------------------------------------------------------------
extern "C" void kernel_launch(void* const* d_in, const int* in_sizes, int n_in,
                              void* d_out, int out_size, void* d_ws, size_t ws_size,
                              hipStream_t stream) {
  const float* x   = (const float*)d_in[0];
  const float* W1  = (const float*)d_in[1];
  const float* W2  = (const float*)d_in[3];
  const float* W3  = (const float*)d_in[5];
  const float* b3  = (const float*)d_in[6];
  const float* g1  = (const float*)d_in[7];
  const float* be1 = (const float*)d_in[8];
  const float* g2  = (const float*)d_in[9];
  const float* be2 = (const float*)d_in[10];

  float* ws = (float*)d_ws;
  float* A          = ws;                 // 131072
  float* Bm         = ws + 131072;        // 131072
  unsigned int* Apf = (unsigned int*)(ws + 262144);  // 65536 uints (fp16 At, permuted)
  unsigned int* Btf = (unsigned int*)(ws + 327680);  // 65536 uints (fp16 Bt, natural)
  unsigned int* w2p = (unsigned int*)(ws + 393216);  // 8192 uints (fp16 W2, fragment)
  float* gs         = ws + 401408;        // 512
  float* sum2       = ws + 401920;        // 256   (contiguous with gs: one memset)
  float* L          = ws + 402176;        // 1048576
  float* out        = (float*)d_out;

  hipMemsetAsync(gs, 0, 768 * sizeof(float), stream);  // gs + sum2

  k_ab<<<288, 256, 0, stream>>>(x, W1, W2, A, Bm, gs, w2p);
  k_fold_apply<<<128, 256, 0, stream>>>(gs, g1, be1, A, Bm, Apf, Btf);
  k_pass<1><<<2048, 256, 0, stream>>>(Apf, Btf, w2p, sum2, nullptr, nullptr, nullptr, nullptr, nullptr);
  k_pass<2><<<2048, 256, 0, stream>>>(Apf, Btf, w2p, sum2, g2, be2, W3, b3, L);
  k_adj<<<4096, 256, 0, stream>>>(L, out);
}

// Round 13
// 207.366 us; speedup vs baseline: 1.2830x; 1.0483x over previous
//
#include <hip/hip_runtime.h>
#include <hip/hip_bf16.h>

typedef _Float16 f16x8 __attribute__((ext_vector_type(8)));
typedef _Float16 f16x4 __attribute__((ext_vector_type(4)));
typedef float    f32x4 __attribute__((ext_vector_type(4)));

#define EPSV 1e-5f

// ---------------------------------------------------------------------------
// K1 (grid 288): blocks 0..255: A = x@Wa^T, B = x@Wb^T + f32 stats atomics;
// A stored RAW fp16 in fragment-permuted layout (128-row slices):
//   half idx = S*16384 + ((s*4+ks)*64 + quad*16 + col)*8 + eh*4 + pos
//   S=j>>7, s=(j>>4)&7, col=j&15, ks=h>>5, quad=(h>>3)&3, eh=(h>>2)&1, pos=h&3
// B stored RAW fp16 natural [i*128+c].
// blocks 256..287: W2 f32 -> fp16 in MFMA B-fragment order (R12 layout).
// ---------------------------------------------------------------------------
__global__ __launch_bounds__(256) void k_ab(const float* __restrict__ x,
                                            const float* __restrict__ W1,
                                            const float* __restrict__ W2,
                                            _Float16* __restrict__ Apf,
                                            _Float16* __restrict__ Btf,
                                            float* __restrict__ gs,
                                            unsigned int* __restrict__ w2p) {
  __shared__ float xs[4 * 128];
  int t = threadIdx.x;
  if (blockIdx.x >= 256) {  // W2 prep -> fp16
    int c = (blockIdx.x - 256) * 256 + t;  // 0..8191
    int pair = c & 3;
    int col  = (c >> 2) & 15;
    int quad = (c >> 6) & 3;
    int nt   = (c >> 8) & 7;
    int ks   = (c >> 11) & 3;
    int k = nt * 16 + col;
    int hch = ks * 32 + quad * 8 + pair * 2;
    _Float16 b0 = (_Float16)W2[k * 128 + hch];
    _Float16 b1 = (_Float16)W2[k * 128 + hch + 1];
    unsigned int u0 = *(unsigned short*)&b0, u1 = *(unsigned short*)&b1;
    w2p[c] = u0 | (u1 << 16);
    return;
  }
  int j0 = blockIdx.x * 4;
  for (int idx = t; idx < 512; idx += 256) xs[idx] = x[j0 * 128 + idx];
  __syncthreads();
  int h = t & 127, half = t >> 7;
  const float4* wrow = (const float4*)(W1 + h * 256 + half * 128);
  const float4* xs4 = (const float4*)xs;
  float a0 = 0.f, a1 = 0.f, a2 = 0.f, a3 = 0.f;
#pragma unroll 8
  for (int ch = 0; ch < 32; ++ch) {
    float4 wv = wrow[ch];
    float4 x0 = xs4[ch], x1 = xs4[32 + ch], x2 = xs4[64 + ch], x3 = xs4[96 + ch];
    a0 += wv.x * x0.x + wv.y * x0.y + wv.z * x0.z + wv.w * x0.w;
    a1 += wv.x * x1.x + wv.y * x1.y + wv.z * x1.z + wv.w * x1.w;
    a2 += wv.x * x2.x + wv.y * x2.y + wv.z * x2.z + wv.w * x2.w;
    a3 += wv.x * x3.x + wv.y * x3.y + wv.z * x3.z + wv.w * x3.w;
  }
  if (half == 0) {
    // raw-A permuted fp16 store (consecutive j -> +8 halfs)
    int S = j0 >> 7, s = (j0 >> 4) & 7, colb = j0 & 15;
    int ks = h >> 5, quad = (h >> 3) & 3, eh = (h >> 2) & 1, pos = h & 3;
    int base = S * 16384 + ((s * 4 + ks) * 64 + quad * 16 + colb) * 8 + eh * 4 + pos;
    Apf[base]      = (_Float16)a0;
    Apf[base + 8]  = (_Float16)a1;
    Apf[base + 16] = (_Float16)a2;
    Apf[base + 24] = (_Float16)a3;
  } else {
    Btf[(j0 + 0) * 128 + h] = (_Float16)a0;
    Btf[(j0 + 1) * 128 + h] = (_Float16)a1;
    Btf[(j0 + 2) * 128 + h] = (_Float16)a2;
    Btf[(j0 + 3) * 128 + h] = (_Float16)a3;
  }
  float s = a0 + a1 + a2 + a3;
  float q = a0 * a0 + a1 * a1 + a2 * a2 + a3 * a3;
  atomicAdd(&gs[half * 256 + h], s);
  atomicAdd(&gs[half * 256 + 128 + h], q);
}

__device__ __forceinline__ void f16x8_to_f32(f16x8 v, f32x4& lo, f32x4& hi) {
  f16x4 l4 = __builtin_shufflevector(v, v, 0, 1, 2, 3);
  f16x4 h4 = __builtin_shufflevector(v, v, 4, 5, 6, 7);
  lo = __builtin_convertvector(l4, f32x4);
  hi = __builtin_convertvector(h4, f32x4);
}
__device__ __forceinline__ f16x8 f32_to_f16x8(f32x4 lo, f32x4 hi) {
  f16x4 l4 = __builtin_convertvector(lo, f16x4);
  f16x4 h4 = __builtin_convertvector(hi, f16x4);
  return __builtin_shufflevector(l4, h4, 0, 1, 2, 3, 4, 5, 6, 7);
}

// ---------------------------------------------------------------------------
// Main pass v13: j-tile 128 (8 s-iters, grid 1024 — 2x prologue amortization
// vs R12) + BN1 fold done in-block (k_fold_apply dispatch eliminated).
// Prologue: stage raw fp16 A slice (32 KB) via global_load_lds; compute
// sc/ta/tb into LDS prm; in-place fold of the slice (each thread folds its
// own uint4s — no cross-thread hazard); Bt rows folded into 32 VGPRs;
// W2 fp16 in 128 VGPRs. Hot loop identical to R12 (one ds_read_b128 per ks).
// PASS1 -> atomicAdd sum2; PASS2 -> logits.
// NOTE: plain __launch_bounds__(256) — min-waves clamps spill 100s of MB
// (R3/R4/R5). NO cooperative launch (R8). W2 stays in regs (R10).
// ---------------------------------------------------------------------------
template <int PASS>
__global__ __launch_bounds__(256) void k_pass(
    const _Float16* __restrict__ Apf, const _Float16* __restrict__ Btf,
    const unsigned int* __restrict__ w2p,
    const float* __restrict__ gs, const float* __restrict__ g1,
    const float* __restrict__ be1,
    float* __restrict__ sum2, const float* __restrict__ g2,
    const float* __restrict__ be2, const float* __restrict__ W3v,
    const float* __restrict__ b3p, float* __restrict__ L) {
  __shared__ unsigned int ats[8192];  // fp16 A slice, raw->folded in place (32 KB)
  __shared__ float red[1024];         // prm (sc|ta|tb, 384) then reductions
  int t = threadIdx.x;
  int bid = blockIdx.x;
  int bj = bid & 7, bi = bid >> 3;
  int lane = t & 63, w = t >> 6;
  int col = lane & 15, quad = lane >> 4;

  // ---- stage raw fp16 A slice (8192 uints, linear): 32 insts, 8/wave ----
  const unsigned int* atsrc = (const unsigned int*)Apf + bj * 8192;
#pragma unroll
  for (int it = 0; it < 8; ++it) {
    int g = w * 8 + it;
    __builtin_amdgcn_global_load_lds(
        (const __attribute__((address_space(1))) unsigned int*)(atsrc + g * 256 + lane * 4),
        (__attribute__((address_space(3))) unsigned int*)(ats + g * 256),
        16, 0, 0);
  }

  // ---- BN1 fold params: sc | ta = be1 - mA*sc | tb = -mB*sc ----
  if (t < 128) {
    const float inv = 1.f / 1024.f;
    float mA = gs[t] * inv;
    float vA = gs[128 + t] * inv - mA * mA;
    float mB = gs[256 + t] * inv;
    float vB = gs[384 + t] * inv - mB * mB;
    float sc = g1[t] * rsqrtf(vA + vB + EPSV);
    red[t] = sc;
    red[128 + t] = be1[t] - mA * sc;
    red[256 + t] = -mB * sc;
  }

  // ---- preload W2 fp16 fragments into 128 VGPRs (global, no LDS dep) ----
  f16x8 bw[4][8];
#pragma unroll
  for (int ks = 0; ks < 4; ++ks)
#pragma unroll
    for (int nt = 0; nt < 8; ++nt)
      bw[ks][nt] = *(const f16x8*)((const _Float16*)w2p + (((ks * 8 + nt) * 64) + lane) * 8);

  float al[8], uu[8], w3l[8];
  float b3v = 0.f;
  if (PASS == 2) {
    b3v = b3p[0];
    const float invM = 1.f / (1024.f * 1024.f);
#pragma unroll
    for (int nt = 0; nt < 8; ++nt) {
      int k = nt * 16 + col;
      float mdot = sum2[k] * invM;
      float var = sum2[128 + k] * invM - mdot * mdot;
      float alv = g2[k] * rsqrtf(var + EPSV);
      al[nt] = alv;
      uu[nt] = be2[k] - mdot * alv;
      w3l[nt] = W3v[k];
    }
  }
  __syncthreads();  // staging done + prm visible

  // ---- in-place fold of A slice: thread t owns uint4s at t*4 + k*1024 ----
  // fixed per thread: col=t&15 (unused), quad=(t>>4)&3, ks=(t>>6)&3; k = s.
  {
    int h0 = ((t >> 6) & 3) * 32 + ((t >> 4) & 3) * 8;
    f32x4 scl = *(const f32x4*)(red + h0);
    f32x4 sch = *(const f32x4*)(red + h0 + 4);
    f32x4 tal = *(const f32x4*)(red + 128 + h0);
    f32x4 tah = *(const f32x4*)(red + 128 + h0 + 4);
#pragma unroll
    for (int k = 0; k < 8; ++k) {
      unsigned int* p = ats + t * 4 + k * 1024;
      f16x8 v = *(f16x8*)p;
      f32x4 lo, hi;
      f16x8_to_f32(v, lo, hi);
      lo = lo * scl + tal;
      hi = hi * sch + tah;
      *(f16x8*)p = f32_to_f16x8(lo, hi);
    }
  }

  // ---- Bt wave rows: raw fp16 -> folded fp16 in 32 VGPRs (s-invariant) ----
  f16x8 btr[2][4];
  {
    int i0 = bi * 8 + w * 2;
#pragma unroll
    for (int r = 0; r < 2; ++r)
#pragma unroll
      for (int ks = 0; ks < 4; ++ks) {
        int hh = ks * 32 + quad * 8;
        f16x8 braw = *(const f16x8*)(Btf + (i0 + r) * 128 + hh);
        f32x4 lo, hi;
        f16x8_to_f32(braw, lo, hi);
        f32x4 sl = *(const f32x4*)(red + hh);
        f32x4 sh = *(const f32x4*)(red + hh + 4);
        f32x4 tl = *(const f32x4*)(red + 256 + hh);
        f32x4 th = *(const f32x4*)(red + 256 + hh + 4);
        lo = lo * sl + tl;
        hi = hi * sh + th;
        btr[r][ks] = f32_to_f16x8(lo, hi);
      }
  }
  __syncthreads();  // fold complete before hot loop

  float s1[8], s2[8];
  if (PASS == 1) {
#pragma unroll
    for (int nt = 0; nt < 8; ++nt) { s1[nt] = 0.f; s2[nt] = 0.f; }
  }

  const f16x8 zz = {(_Float16)0, (_Float16)0, (_Float16)0, (_Float16)0,
                    (_Float16)0, (_Float16)0, (_Float16)0, (_Float16)0};

  for (int s = 0; s < 8; ++s) {
    f32x4 acc[2][8];
#pragma unroll
    for (int mt = 0; mt < 2; ++mt)
#pragma unroll
      for (int nt = 0; nt < 8; ++nt) acc[mt][nt] = (f32x4){0.f, 0.f, 0.f, 0.f};

#pragma unroll
    for (int ks = 0; ks < 4; ++ks) {
      f16x8 af = *(const f16x8*)(ats + ((s * 4 + ks) * 64 + lane) * 4);
      f16x8 a0 = __builtin_elementwise_max(af + btr[0][ks], zz);
      f16x8 a1 = __builtin_elementwise_max(af + btr[1][ks], zz);
#pragma unroll
      for (int nt = 0; nt < 8; ++nt) {
        acc[0][nt] = __builtin_amdgcn_mfma_f32_16x16x32_f16(a0, bw[ks][nt], acc[0][nt], 0, 0, 0);
        acc[1][nt] = __builtin_amdgcn_mfma_f32_16x16x32_f16(a1, bw[ks][nt], acc[1][nt], 0, 0, 0);
      }
    }

    if (PASS == 1) {
#pragma unroll
      for (int nt = 0; nt < 8; ++nt)
#pragma unroll
        for (int mt = 0; mt < 2; ++mt)
#pragma unroll
          for (int r = 0; r < 4; ++r) {
            float d = acc[mt][nt][r];
            s1[nt] += d;
            s2[nt] = fmaf(d, d, s2[nt]);
          }
    } else {
#pragma unroll
      for (int mt = 0; mt < 2; ++mt) {
        float rsum[4] = {0.f, 0.f, 0.f, 0.f};
#pragma unroll
        for (int nt = 0; nt < 8; ++nt)
#pragma unroll
          for (int r = 0; r < 4; ++r) {
            float h = fmaxf(fmaf(acc[mt][nt][r], al[nt], uu[nt]), 0.f);
            rsum[r] = fmaf(h, w3l[nt], rsum[r]);
          }
#pragma unroll
        for (int r = 0; r < 4; ++r) {
          rsum[r] += __shfl_xor(rsum[r], 1);
          rsum[r] += __shfl_xor(rsum[r], 2);
          rsum[r] += __shfl_xor(rsum[r], 4);
          rsum[r] += __shfl_xor(rsum[r], 8);
        }
        if (col == 0) {
          int i = bi * 8 + w * 2 + mt;
          float4 v = make_float4(rsum[0] + b3v, rsum[1] + b3v,
                                 rsum[2] + b3v, rsum[3] + b3v);
          *(float4*)(&L[i * 1024 + bj * 128 + s * 16 + quad * 4]) = v;
        }
      }
    }
  }

  if (PASS == 1) {
#pragma unroll
    for (int nt = 0; nt < 8; ++nt) {
      s1[nt] += __shfl_xor(s1[nt], 16);
      s1[nt] += __shfl_xor(s1[nt], 32);
      s2[nt] += __shfl_xor(s2[nt], 16);
      s2[nt] += __shfl_xor(s2[nt], 32);
    }
    __syncthreads();  // prm dead; red reused for reduction
    if (lane < 16) {
#pragma unroll
      for (int nt = 0; nt < 8; ++nt) {
        red[w * 256 + nt * 16 + lane] = s1[nt];
        red[w * 256 + 128 + nt * 16 + lane] = s2[nt];
      }
    }
    __syncthreads();
    float tot = red[t] + red[256 + t] + red[512 + t] + red[768 + t];
    atomicAdd(&sum2[t], tot);
  }
}

// ---------------------------------------------------------------------------
// K5: adj[i,j] = (i==j) ? 0 : sigmoid(0.5*(L[i,j]+L[j,i])). grid 4096 x 256.
// ---------------------------------------------------------------------------
__global__ __launch_bounds__(256) void k_adj(const float* __restrict__ L,
                                             float* __restrict__ out) {
  int idx = blockIdx.x * 256 + threadIdx.x;
  int i = idx >> 10, j = idx & 1023;
  float a = L[i * 1024 + j];
  float b = L[j * 1024 + i];
  float s = 1.f / (1.f + __expf(-0.5f * (a + b)));
  out[idx] = (i == j) ? 0.f : s;
}

// ---------------------------------------------------------------------------
extern "C" void kernel_launch(void* const* d_in, const int* in_sizes, int n_in,
                              void* d_out, int out_size, void* d_ws, size_t ws_size,
                              hipStream_t stream) {
  const float* x   = (const float*)d_in[0];
  const float* W1  = (const float*)d_in[1];
  const float* W2  = (const float*)d_in[3];
  const float* W3  = (const float*)d_in[5];
  const float* b3  = (const float*)d_in[6];
  const float* g1  = (const float*)d_in[7];
  const float* be1 = (const float*)d_in[8];
  const float* g2  = (const float*)d_in[9];
  const float* be2 = (const float*)d_in[10];

  float* ws = (float*)d_ws;
  _Float16* Apf     = (_Float16*)ws;                 // 131072 halfs (raw A, permuted)
  _Float16* Btf     = (_Float16*)(ws + 65536);       // 131072 halfs (raw B, natural)
  unsigned int* w2p = (unsigned int*)(ws + 131072);  // 8192 uints (fp16 W2, fragment)
  float* gs         = ws + 139264;        // 512
  float* sum2       = ws + 139776;        // 256   (contiguous with gs: one memset)
  float* L          = ws + 140032;        // 1048576
  float* out        = (float*)d_out;

  hipMemsetAsync(gs, 0, 768 * sizeof(float), stream);  // gs + sum2

  k_ab<<<288, 256, 0, stream>>>(x, W1, W2, Apf, Btf, gs, w2p);
  k_pass<1><<<1024, 256, 0, stream>>>(Apf, Btf, w2p, gs, g1, be1, sum2,
                                      nullptr, nullptr, nullptr, nullptr, nullptr);
  k_pass<2><<<1024, 256, 0, stream>>>(Apf, Btf, w2p, gs, g1, be1, sum2,
                                      g2, be2, W3, b3, L);
  k_adj<<<4096, 256, 0, stream>>>(L, out);
}